// Round 1
// baseline (729.589 us; speedup 1.0000x reference)
//
#include <hip/hip_runtime.h>
#include <math.h>

// Problem constants (fixed by setup_inputs)
#define CCH 16
#define HH 256
#define WW 512
#define ND 32
#define HWSZ (HH * WW)
#define BASELINE 0.24f

__global__ __launch_bounds__(256) void cost_volume_kernel(
    const float* __restrict__ x,
    const float* __restrict__ y,
    const float* __restrict__ depth,
    float* __restrict__ out)
{
    int tid = blockIdx.x * blockDim.x + threadIdx.x;   // over ND*H*W
    if (tid >= ND * HWSZ) return;

    int w = tid & (WW - 1);
    int h = (tid >> 9) & (HH - 1);
    int d = tid >> 17;
    int p = h * WW + w;

    float dep = depth[d * HWSZ + p];

    // theta for this row (equirectangular, pixel-centered)
    float theta = ((float)h + 0.5f) * (float)(M_PI / HH) - (float)(M_PI / 2.0);
    float st, ct;
    sincosf(theta, &st, &ct);

    // vertical angular shift -> pixel rows
    float dth = atanf((dep * st + BASELINE) / (dep * ct)) - theta;
    float d_v = dth * (float)(HH / M_PI);
    float y_px = isfinite(d_v) ? ((float)h + d_v) : 0.0f;

    // faithful grid_sample(align_corners=False) unnormalization,
    // same arithmetic order as the reference
    float cx = (float)w / ((WW - 1.0f) * 0.5f) - 1.0f;
    float cy = y_px   / ((HH - 1.0f) * 0.5f) - 1.0f;
    float ix = ((cx + 1.0f) * (float)WW - 1.0f) * 0.5f;
    float iy = ((cy + 1.0f) * (float)HH - 1.0f) * 0.5f;

    float x0f = floorf(ix);
    float y0f = floorf(iy);
    float wx1 = ix - x0f;
    float wy1 = iy - y0f;
    float wx0 = 1.0f - wx1;
    float wy0 = 1.0f - wy1;

    int x0 = (int)x0f;
    int y0 = (int)y0f;
    int x1 = x0 + 1;
    int y1 = y0 + 1;

    float vx0 = (x0 >= 0 && x0 <= WW - 1) ? 1.0f : 0.0f;
    float vx1 = (x1 >= 0 && x1 <= WW - 1) ? 1.0f : 0.0f;
    float vy0 = (y0 >= 0 && y0 <= HH - 1) ? 1.0f : 0.0f;
    float vy1 = (y1 >= 0 && y1 <= HH - 1) ? 1.0f : 0.0f;

    int x0c = min(max(x0, 0), WW - 1);
    int x1c = min(max(x1, 0), WW - 1);
    int y0c = min(max(y0, 0), HH - 1);
    int y1c = min(max(y1, 0), HH - 1);

    float w00 = wx0 * wy0 * vx0 * vy0;
    float w10 = wx1 * wy0 * vx1 * vy0;
    float w01 = wx0 * wy1 * vx0 * vy1;
    float w11 = wx1 * wy1 * vx1 * vy1;

    int f00 = y0c * WW + x0c;
    int f10 = y0c * WW + x1c;
    int f01 = y1c * WW + x0c;
    int f11 = y1c * WW + x1c;

    int dp = d * HWSZ + p;

    #pragma unroll
    for (int c = 0; c < CCH; ++c) {
        int cb = c * HWSZ;
        float v00 = y[cb + f00];
        float v10 = y[cb + f10];
        float v01 = y[cb + f01];
        float v11 = y[cb + f11];
        float val = v00 * w00 + v10 * w10 + v01 * w01 + v11 * w11;

        // reference half: broadcast x over disparity
        out[(size_t)(c * ND) * HWSZ + dp] = x[cb + p];
        // warped half
        out[(size_t)((CCH + c) * ND) * HWSZ + dp] = val;
    }
}

extern "C" void kernel_launch(void* const* d_in, const int* in_sizes, int n_in,
                              void* d_out, int out_size, void* d_ws, size_t ws_size,
                              hipStream_t stream) {
    const float* x = (const float*)d_in[0];
    const float* y = (const float*)d_in[1];
    const float* depth = (const float*)d_in[2];
    float* out = (float*)d_out;

    int total = ND * HWSZ;                 // 4,194,304 threads
    int block = 256;
    int grid = (total + block - 1) / block;
    cost_volume_kernel<<<grid, block, 0, stream>>>(x, y, depth, out);
}

// Round 2
// 663.382 us; speedup vs baseline: 1.0998x; 1.0998x over previous
//
#include <hip/hip_runtime.h>
#include <math.h>

// Problem constants (fixed by setup_inputs)
#define CCH 16
#define HH 256
#define WW 512
#define ND 32
#define HWSZ (HH * WW)
#define BASELINE 0.24f

// Pass 1: transpose y [C,H,W] -> yt [H,W,C] (channel-innermost, 64B per pixel)
__global__ __launch_bounds__(256) void transpose_y_kernel(
    const float* __restrict__ y, float* __restrict__ yt)
{
    int p = blockIdx.x * blockDim.x + threadIdx.x;  // pixel index over H*W
    if (p >= HWSZ) return;
    float v[CCH];
    #pragma unroll
    for (int c = 0; c < CCH; ++c) v[c] = y[c * HWSZ + p];
    float4* dst = (float4*)(yt + (size_t)p * CCH);
    #pragma unroll
    for (int j = 0; j < 4; ++j)
        dst[j] = make_float4(v[4 * j], v[4 * j + 1], v[4 * j + 2], v[4 * j + 3]);
}

// Pass 2: fused broadcast + warp-gather.
// Block: 256 threads = 4 disparities x 64 w-pixels (shared (h,w) neighborhood
// across d for y-row L2 reuse). Grid: (W/64, H, ND/4).
__global__ __launch_bounds__(256) void cost_volume_kernel(
    const float* __restrict__ x,
    const float4* __restrict__ yt4,   // [H*W][4] float4 (channel-innermost)
    const float* __restrict__ depth,
    float* __restrict__ out)
{
    int w = blockIdx.x * 64 + (threadIdx.x & 63);
    int h = blockIdx.y;
    int d = blockIdx.z * 4 + (threadIdx.x >> 6);
    int p = h * WW + w;

    float dep = depth[d * HWSZ + p];

    // theta for this row (equirectangular, pixel-centered)
    float theta = ((float)h + 0.5f) * (float)(M_PI / HH) - (float)(M_PI / 2.0);
    float st, ct;
    sincosf(theta, &st, &ct);

    // vertical angular shift -> pixel rows
    float dth = atanf((dep * st + BASELINE) / (dep * ct)) - theta;
    float d_v = dth * (float)(HH / M_PI);
    float y_px = isfinite(d_v) ? ((float)h + d_v) : 0.0f;

    // faithful grid_sample(align_corners=False) unnormalization,
    // same arithmetic order as the reference
    float cx = (float)w / ((WW - 1.0f) * 0.5f) - 1.0f;
    float cy = y_px   / ((HH - 1.0f) * 0.5f) - 1.0f;
    float ix = ((cx + 1.0f) * (float)WW - 1.0f) * 0.5f;
    float iy = ((cy + 1.0f) * (float)HH - 1.0f) * 0.5f;

    float x0f = floorf(ix);
    float y0f = floorf(iy);
    float wx1 = ix - x0f;
    float wy1 = iy - y0f;
    float wx0 = 1.0f - wx1;
    float wy0 = 1.0f - wy1;

    int x0 = (int)x0f;
    int y0 = (int)y0f;
    int x1 = x0 + 1;
    int y1 = y0 + 1;

    float vx0 = (x0 >= 0 && x0 <= WW - 1) ? 1.0f : 0.0f;
    float vx1 = (x1 >= 0 && x1 <= WW - 1) ? 1.0f : 0.0f;
    float vy0 = (y0 >= 0 && y0 <= HH - 1) ? 1.0f : 0.0f;
    float vy1 = (y1 >= 0 && y1 <= HH - 1) ? 1.0f : 0.0f;

    int x0c = min(max(x0, 0), WW - 1);
    int x1c = min(max(x1, 0), WW - 1);
    int y0c = min(max(y0, 0), HH - 1);
    int y1c = min(max(y1, 0), HH - 1);

    float w00 = wx0 * wy0 * vx0 * vy0;
    float w10 = wx1 * wy0 * vx1 * vy0;
    float w01 = wx0 * wy1 * vx0 * vy1;
    float w11 = wx1 * wy1 * vx1 * vy1;

    // corner bases in float4 units (each corner = 16 floats = 4 float4 = 64B)
    int b00 = (y0c * WW + x0c) * 4;
    int b10 = (y0c * WW + x1c) * 4;
    int b01 = (y1c * WW + x0c) * 4;
    int b11 = (y1c * WW + x1c) * 4;

    float4 acc[4];
    #pragma unroll
    for (int j = 0; j < 4; ++j) {
        float4 a = yt4[b00 + j];
        acc[j] = make_float4(a.x * w00, a.y * w00, a.z * w00, a.w * w00);
    }
    #pragma unroll
    for (int j = 0; j < 4; ++j) {
        float4 a = yt4[b10 + j];
        acc[j].x += a.x * w10; acc[j].y += a.y * w10;
        acc[j].z += a.z * w10; acc[j].w += a.w * w10;
    }
    #pragma unroll
    for (int j = 0; j < 4; ++j) {
        float4 a = yt4[b01 + j];
        acc[j].x += a.x * w01; acc[j].y += a.y * w01;
        acc[j].z += a.z * w01; acc[j].w += a.w * w01;
    }
    #pragma unroll
    for (int j = 0; j < 4; ++j) {
        float4 a = yt4[b11 + j];
        acc[j].x += a.x * w11; acc[j].y += a.y * w11;
        acc[j].z += a.z * w11; acc[j].w += a.w * w11;
    }

    const float* accf = (const float*)acc;
    size_t dp = (size_t)d * HWSZ + p;

    #pragma unroll
    for (int c = 0; c < CCH; ++c) {
        // reference half: broadcast x over disparity
        out[(size_t)c * (ND * HWSZ) + dp] = x[c * HWSZ + p];
        // warped half
        out[(size_t)(CCH + c) * (ND * HWSZ) + dp] = accf[c];
    }
}

extern "C" void kernel_launch(void* const* d_in, const int* in_sizes, int n_in,
                              void* d_out, int out_size, void* d_ws, size_t ws_size,
                              hipStream_t stream) {
    const float* x = (const float*)d_in[0];
    const float* y = (const float*)d_in[1];
    const float* depth = (const float*)d_in[2];
    float* out = (float*)d_out;
    float* yt = (float*)d_ws;   // needs H*W*16*4 = 8 MB

    transpose_y_kernel<<<(HWSZ + 255) / 256, 256, 0, stream>>>(y, yt);

    dim3 grid(WW / 64, HH, ND / 4);
    cost_volume_kernel<<<grid, 256, 0, stream>>>(x, (const float4*)yt, depth, out);
}